// Round 10
// baseline (711.731 us; speedup 1.0000x reference)
//
#include <hip/hip_runtime.h>
#include <hip/hip_bf16.h>

#define DIMX  4096
#define KROT  8
#define GRP   128
#define NGG   32
#define NROWS 16384
#define RT2   64                   // rows per task
#define NT2   (NROWS / RT2)        // 256 row tiles
#define GPG   32                   // row-tile strides per group
#define GRID2 (NGG * GPG)          // 1024 blocks = 4/CU

typedef float f32x4 __attribute__((ext_vector_type(4)));
typedef short s16x8 __attribute__((ext_vector_type(8)));
typedef unsigned int u32;
typedef u32 u32x4 __attribute__((ext_vector_type(4)));
typedef unsigned short u16;

// ---------------------------------------------------------------------------
// Compose the 8 rotation rounds (+ channel scale) into one 128x128 matrix per
// group; emit B = M'^T as bf16 hi/lo in MFMA-fragment-linear order.
// Chunk(g,w,ks,nt,hl): 64 lanes x 8 bf16, 16B/lane. (Verified R2/R7.)
// ---------------------------------------------------------------------------
__global__ __launch_bounds__(512) void compose(const float* __restrict__ theta,
                                               const int*   __restrict__ pairs,
                                               const float* __restrict__ scales,
                                               u16* __restrict__ B) {
    __shared__ float M[GRP * GRP];           // M[r*128 + d]
    const int g = blockIdx.x;
    const int tid = threadIdx.x;
    const int j = tid & 127, q = tid >> 7;

    for (int r = q * 32; r < q * 32 + 32; ++r) M[r * GRP + j] = (r == j) ? 1.f : 0.f;
    __syncthreads();

    for (int k = 0; k < KROT; ++k) {
        for (int t = 0; t < 16; ++t) {
            int tp = q * 16 + t;
            int ie = pairs[k * DIMX + g * GRP + 2 * tp];
            int io = pairs[k * DIMX + g * GRP + 2 * tp + 1];
            float ang = theta[k * (DIMX / 2) + g * 64 + tp];
            float c = cosf(ang), s = sinf(ang);
            float a = M[ie * GRP + j], b = M[io * GRP + j];
            M[ie * GRP + j] = a * c - b * s;
            M[io * GRP + j] = a * s + b * c;
        }
        __syncthreads();
    }

    const int l = tid & 63, nt = (tid >> 6) & 1, ks = (tid >> 7) & 3;
    for (int w = 0; w < 4; ++w) {
        int c = w * 32 + nt * 16 + (l & 15);
        float sc = scales[g * GRP + c];
        int dbase = ks * 32 + ((l >> 4) & 3) * 8;
        s16x8 vh, vl;
        #pragma unroll
        for (int e = 0; e < 8; ++e) {
            float v = sc * M[c * GRP + dbase + e];
            __hip_bfloat16 h = __float2bfloat16(v);
            float r = v - __bfloat162float(h);
            __hip_bfloat16 lo = __float2bfloat16(r);
            u16 hb, lb2;
            __builtin_memcpy(&hb, &h, 2);
            __builtin_memcpy(&lb2, &lo, 2);
            vh[e] = (short)hb;
            vl[e] = (short)lb2;
        }
        int off = (((g * 4 + w) * 4 + ks) * 2 + nt) * 2;
        *(s16x8*)(B + (size_t)(off + 0) * 512 + l * 8) = vh;
        *(s16x8*)(B + (size_t)(off + 1) * 512 + l * 8) = vl;
    }
}

// ---------------------------------------------------------------------------
// Main: out[n, g*128+c] = sum_d x[n, g*128+d] * B_g[d][c]
// A: direct global->VGPR, 2-strip register double-buffer (strip m+1 loads in
// flight during strip m convert+MFMA). RNE hi/lo split via v_cvt_pk path.
// C: acc -> swizzled LDS (2-way writes, free) -> coalesced dwordx4 stores.
// ---------------------------------------------------------------------------
__global__ __launch_bounds__(256, 4) void rot_gemm(const float* __restrict__ x,
                                                   const u16* __restrict__ B,
                                                   float* __restrict__ out) {
    __shared__ __align__(16) float C[RT2 * GRP];   // 32 KiB transpose buffer
    const int tid = threadIdx.x;
    const int l  = tid & 63, wv = tid >> 6;
    const int lr = l & 15;          // fragment row within a 16-row strip
    const int lq = (l >> 4) & 3;    // k-quad within a 32-elem k-slice
    const int g  = blockIdx.x & 31; // group fixed per block -> B loads L2-hot

    // B fragments: hi/lo, this wave's 32-col slice, all 4 k-slices
    s16x8 bh[4][2], bl[4][2];
    #pragma unroll
    for (int ks = 0; ks < 4; ++ks)
        #pragma unroll
        for (int nt = 0; nt < 2; ++nt) {
            int off = (((g * 4 + wv) * 4 + ks) * 2 + nt) * 2;
            bh[ks][nt] = *(const s16x8*)(B + (size_t)(off + 0) * 512 + l * 8);
            bl[ks][nt] = *(const s16x8*)(B + (size_t)(off + 1) * 512 + l * 8);
        }

    for (int rt = blockIdx.x >> 5; rt < NT2; rt += GPG) {
        const float* xt = x + (size_t)(rt * RT2) * DIMX + g * GRP;
        f32x4 A0[2][4], A1[2][4];        // 2-strip double buffer (static idx)

        #pragma unroll
        for (int ks = 0; ks < 4; ++ks) { // preload strip 0
            const float* p = xt + (size_t)(0 * 16 + lr) * DIMX + ks * 32 + lq * 8;
            A0[0][ks] = *(const f32x4*)p;
            A1[0][ks] = *(const f32x4*)(p + 4);
        }

        f32x4 acc[4][2] = {};
        #pragma unroll
        for (int m = 0; m < 4; ++m) {    // full unroll: all buffer idx static
            const int cur = m & 1, nxt = cur ^ 1;
            if (m < 3) {
                #pragma unroll
                for (int ks = 0; ks < 4; ++ks) {   // next strip: issue early
                    const float* p = xt + (size_t)((m + 1) * 16 + lr) * DIMX + ks * 32 + lq * 8;
                    A0[nxt][ks] = *(const f32x4*)p;
                    A1[nxt][ks] = *(const f32x4*)(p + 4);
                }
            }
            #pragma unroll
            for (int ks = 0; ks < 4; ++ks) {
                u32x4 hd, ld;
                #pragma unroll
                for (int j = 0; j < 4; ++j) {      // pairs (2j, 2j+1)
                    float v0 = (j < 2) ? A0[cur][ks][2 * j]     : A1[cur][ks][2 * j - 4];
                    float v1 = (j < 2) ? A0[cur][ks][2 * j + 1] : A1[cur][ks][2 * j - 3];
                    __hip_bfloat162 hb = __float22bfloat162_rn(make_float2(v0, v1));
                    float r0 = v0 - __bfloat162float(hb.x);
                    float r1 = v1 - __bfloat162float(hb.y);
                    __hip_bfloat162 lb = __float22bfloat162_rn(make_float2(r0, r1));
                    u32 hw, lw;
                    __builtin_memcpy(&hw, &hb, 4);   // bf162 struct -> u32 (packed)
                    __builtin_memcpy(&lw, &lb, 4);
                    hd[j] = hw;
                    ld[j] = lw;
                }
                s16x8 ah = __builtin_bit_cast(s16x8, hd);
                s16x8 al = __builtin_bit_cast(s16x8, ld);
                #pragma unroll
                for (int nt = 0; nt < 2; ++nt) {
                    acc[m][nt] = __builtin_amdgcn_mfma_f32_16x16x32_bf16(ah, bh[ks][nt], acc[m][nt], 0, 0, 0);
                    acc[m][nt] = __builtin_amdgcn_mfma_f32_16x16x32_bf16(ah, bl[ks][nt], acc[m][nt], 0, 0, 0);
                    acc[m][nt] = __builtin_amdgcn_mfma_f32_16x16x32_bf16(al, bh[ks][nt], acc[m][nt], 0, 0, 0);
                }
            }
        }

        // acc -> LDS, col XOR-swizzled by (row&12)<<2: ds_write 2-way (free)
        #pragma unroll
        for (int m = 0; m < 4; ++m)
            #pragma unroll
            for (int nt = 0; nt < 2; ++nt)
                #pragma unroll
                for (int i = 0; i < 4; ++i) {
                    int row = m * 16 + lq * 4 + i;
                    int col = wv * 32 + nt * 16 + lr;
                    C[row * GRP + (col ^ ((row & 12) << 2))] = acc[m][nt][i];
                }
        __syncthreads();

        // coalesced store: 32 lanes x float4 = full 512B rows
        float* ob = out + (size_t)(rt * RT2) * DIMX + g * GRP;
        #pragma unroll
        for (int j = 0; j < 8; ++j) {
            int flat = j * 256 + tid;
            int row = flat >> 5, c4 = (flat & 31) * 4;
            f32x4 v = *(const f32x4*)&C[row * GRP + (c4 ^ ((row & 12) << 2))];
            *(f32x4*)(ob + (size_t)row * DIMX + c4) = v;
        }
        __syncthreads();   // LDS reuse guard for next tile
    }
}

extern "C" void kernel_launch(void* const* d_in, const int* in_sizes, int n_in,
                              void* d_out, int out_size, void* d_ws, size_t ws_size,
                              hipStream_t stream) {
    const float* xin    = (const float*)d_in[0];
    const int*   pairs  = (const int*)d_in[1];
    const float* theta  = (const float*)d_in[2];
    const float* scales = (const float*)d_in[3];
    float* outp = (float*)d_out;
    u16*   Btab = (u16*)d_ws;                 // 2 MiB fragment table

    compose<<<NGG, 512, 0, stream>>>(theta, pairs, scales, Btab);
    rot_gemm<<<GRID2, 256, 0, stream>>>(xin, Btab, outp);
}